// Round 18
// baseline (388.459 us; speedup 1.0000x reference)
//
#include <hip/hip_runtime.h>
#include <math.h>

#define DIN 64
#define NB_MAX 512   // buckets of 256 nodes: supports N <= 131072
#define S1_CHUNK 4096

typedef unsigned short us8 __attribute__((ext_vector_type(8)));
typedef short s16x8 __attribute__((ext_vector_type(8)));
typedef float f32x4 __attribute__((ext_vector_type(4)));

// ---------------- bf16 helpers (RNE) ----------------

__device__ __forceinline__ float bf2f(unsigned short u) {
    return __uint_as_float(((unsigned int)u) << 16);
}
__device__ __forceinline__ unsigned short f2bf(float f) {
    unsigned int u = __float_as_uint(f);
    return (unsigned short)((u + 0x7fffu + ((u >> 16) & 1u)) >> 16);
}

// ---------------- per-BUCKET histogram ----------------

__global__ __launch_bounds__(256) void bcount_kernel(const int* __restrict__ col,
                                                     int* __restrict__ bcnt, int E, int NB) {
    __shared__ int cntB[NB_MAX];
    for (int t = threadIdx.x; t < NB; t += 256) cntB[t] = 0;
    __syncthreads();
    int stride = gridDim.x * blockDim.x;
    for (int i = blockIdx.x * blockDim.x + threadIdx.x; i < E; i += stride)
        atomicAdd(&cntB[col[i] >> 8], 1);
    __syncthreads();
    for (int t = threadIdx.x; t < NB; t += 256) {
        int c = cntB[t];
        if (c) atomicAdd(&bcnt[t], c);
    }
}

__global__ void bscan_kernel(const int* __restrict__ bcnt, int* __restrict__ bbase,
                             int* __restrict__ gcur, int* __restrict__ rowptr,
                             int NB, int N, int E) {
    __shared__ int sm[512];
    int tid = threadIdx.x;
    int v = (tid < NB) ? bcnt[tid] : 0;
    sm[tid] = v;
    __syncthreads();
    for (int off = 1; off < 512; off <<= 1) {
        int add = (tid >= off) ? sm[tid - off] : 0;
        __syncthreads();
        sm[tid] += add;
        __syncthreads();
    }
    if (tid < NB) { int b = sm[tid] - v; bbase[tid] = b; gcur[tid] = b; }
    if (tid == NB - 1) bbase[NB] = sm[tid];
    if (tid == 0) rowptr[N] = E;
}

// ---------------- S1: bucket scatter (entry packed (src<<8)|(dest&255)) ----------------

__global__ __launch_bounds__(256) void s1_bucket(const int* __restrict__ row,
                                                 const int* __restrict__ col,
                                                 int* __restrict__ gcur,
                                                 int* __restrict__ sorted, int E, int NB) {
    __shared__ int2 ebuf[S1_CHUNK];      // 32KB
    __shared__ int cntL[NB_MAX];
    __shared__ int baseL[NB_MAX];
    __shared__ int curL[NB_MAX];
    __shared__ int gbaseL[NB_MAX];
    __shared__ int sm[256];
    int tid = threadIdx.x;
    int jb = blockIdx.x * S1_CHUNK;
    int je = min(jb + S1_CHUNK, E);
    int cntTot = je - jb;

    for (int t = tid; t < NB; t += 256) cntL[t] = 0;
    __syncthreads();
    for (int j = jb + tid; j < je; j += 256) atomicAdd(&cntL[col[j] >> 8], 1);
    __syncthreads();
    int per = (NB + 255) >> 8;
    int s = 0;
    for (int q = 0; q < per; ++q) {
        int idx = tid * per + q;
        if (idx < NB) s += cntL[idx];
    }
    sm[tid] = s;
    __syncthreads();
    for (int off = 1; off < 256; off <<= 1) {
        int add = (tid >= off) ? sm[tid - off] : 0;
        __syncthreads();
        sm[tid] += add;
        __syncthreads();
    }
    int run = sm[tid] - s;
    for (int q = 0; q < per; ++q) {
        int idx = tid * per + q;
        if (idx < NB) { baseL[idx] = run; curL[idx] = run; run += cntL[idx]; }
    }
    __syncthreads();
    for (int t = tid; t < NB; t += 256)
        gbaseL[t] = atomicAdd(&gcur[t], cntL[t]);
    for (int j = jb + tid; j < je; j += 256) {
        int c = col[j];
        int pos = atomicAdd(&curL[c >> 8], 1);
        ebuf[pos] = make_int2(row[j], c);
    }
    __syncthreads();
    for (int jj = tid; jj < cntTot; jj += 256) {
        int2 e = ebuf[jj];
        int t = e.y >> 8;
        sorted[gbaseL[t] + (jj - baseL[t])] = (e.x << 8) | (e.y & 255);
    }
}

// ---------------- S2: per-bucket counts + rowptr + dinv/rdinv + src placement --------

__global__ __launch_bounds__(256) void s2_kernel(const int* __restrict__ sorted,
                                                 const int* __restrict__ bbase,
                                                 int* __restrict__ rowptr,
                                                 float* __restrict__ dinv,
                                                 float* __restrict__ rdinv,
                                                 int* __restrict__ srcarr, int N) {
    __shared__ int cntL[256], baseL[256], sm[256];
    int tid = threadIdx.x;
    int b = blockIdx.x;
    int c0 = b << 8;
    int nLoc = min(256, N - c0);
    int gs = bbase[b], ge = bbase[b + 1];
    cntL[tid] = 0;
    __syncthreads();
    for (int j = gs + tid; j < ge; j += 256)
        atomicAdd(&cntL[sorted[j] & 255], 1);
    __syncthreads();
    int c = cntL[tid];
    sm[tid] = c;
    __syncthreads();
    for (int off = 1; off < 256; off <<= 1) {
        int add = (tid >= off) ? sm[tid - off] : 0;
        __syncthreads();
        sm[tid] += add;
        __syncthreads();
    }
    int base = gs + sm[tid] - c;
    baseL[tid] = base;
    if (tid < nLoc) {
        rowptr[c0 + tid] = base;
        dinv[c0 + tid] = (c > 0) ? rsqrtf((float)c) : 0.0f;
        rdinv[c0 + tid] = (c > 0) ? sqrtf((float)c) : 0.0f;
    }
    cntL[tid] = 0;  // reuse as cursor
    __syncthreads();
    for (int j = gs + tid; j < ge; j += 256) {
        int e = sorted[j];
        int cl = e & 255;
        int p = baseL[cl] + atomicAdd(&cntL[cl], 1);
        srcarr[p] = e >> 8;
    }
}

// ---------------- cvt: x -> hb0 (bf16) and sb0 = dinv*x ----------------

__global__ void cvt_kernel(const float* __restrict__ x, const float* __restrict__ dinv,
                           unsigned short* __restrict__ hb0, unsigned short* __restrict__ sb0,
                           int n4) {
    int i = blockIdx.x * blockDim.x + threadIdx.x;
    if (i >= n4) return;
    float d = dinv[i >> 4];
    float4 v = *(const float4*)&x[(size_t)i * 4];
    ushort4 h, s;
    h.x = f2bf(v.x); h.y = f2bf(v.y); h.z = f2bf(v.z); h.w = f2bf(v.w);
    s.x = f2bf(d * v.x); s.y = f2bf(d * v.y); s.z = f2bf(d * v.z); s.w = f2bf(d * v.w);
    *(ushort4*)&hb0[(size_t)i * 4] = h;
    *(ushort4*)&sb0[(size_t)i * 4] = s;
}

// ---------------- propagation, 64-dim (layer 1) ----------------

__global__ __launch_bounds__(256) void prop_kernel(const int* __restrict__ rowptr,
                                                   const int* __restrict__ srcarr,
                                                   const float* __restrict__ dinv,
                                                   const unsigned short* __restrict__ sb_in,
                                                   unsigned short* __restrict__ sb_out, int N) {
    int gid = blockIdx.x * blockDim.x + threadIdx.x;
    int node = gid >> 6;
    if (node >= N) return;
    int lane = threadIdx.x & 63;
    int g = lane >> 3, l = lane & 7;
    int beg = rowptr[node], end = rowptr[node + 1];
    int deg = end - beg;
    float a[8] = {};
    for (int chunk = 0; chunk < deg; chunk += 64) {
        int lim = min(64, deg - chunk);           // wave-uniform
        int src_l = (lane < lim) ? srcarr[beg + chunk + lane] : 0;
        int iters = (lim + 7) >> 3;               // wave-uniform
        for (int t = 0; t < iters; ++t) {
            int jj = g + (t << 3);
            int src = __shfl(src_l, jj, 64);      // all 64 lanes active
            if (jj < lim) {
                us8 hv = *(const us8*)&sb_in[(size_t)src * DIN + l * 8];
#pragma unroll
                for (int k = 0; k < 8; ++k) a[k] += bf2f(hv[k]);
            }
        }
    }
#pragma unroll
    for (int off = 8; off < 64; off <<= 1) {
#pragma unroll
        for (int k = 0; k < 8; ++k) a[k] += __shfl_xor(a[k], off, 64);
    }
    if (g == 0) {
        float d = dinv[node];
        float d2 = d * d;
        us8 o;
#pragma unroll
        for (int k = 0; k < 8; ++k) o[k] = f2bf(d2 * a[k]);
        *(us8*)&sb_out[(size_t)node * DIN + l * 8] = o;
    }
}

// ---------------- propagation, 40-dim packed (layer 2, Horner) ----------------

template <bool ADDIN>
__global__ __launch_bounds__(256) void prop40_kernel(const int* __restrict__ rowptr,
                                                     const int* __restrict__ srcarr,
                                                     const float* __restrict__ dinv,
                                                     const unsigned short* __restrict__ in,
                                                     const unsigned short* __restrict__ addin,
                                                     unsigned short* __restrict__ out, int N) {
    int gid = blockIdx.x * blockDim.x + threadIdx.x;
    int node = gid >> 6;
    if (node >= N) return;
    int lane = threadIdx.x & 63;
    int g = lane >> 3, l = lane & 7;
    int beg = rowptr[node], end = rowptr[node + 1];
    int deg = end - beg;
    float a[8] = {};
    for (int chunk = 0; chunk < deg; chunk += 64) {
        int lim = min(64, deg - chunk);
        int src_l = (lane < lim) ? srcarr[beg + chunk + lane] : 0;
        int iters = (lim + 7) >> 3;
        for (int t = 0; t < iters; ++t) {
            int jj = g + (t << 3);
            int src = __shfl(src_l, jj, 64);      // all lanes active
            if (jj < lim && l < 5) {
                us8 hv = *(const us8*)&in[(size_t)src * 40 + l * 8];
#pragma unroll
                for (int k = 0; k < 8; ++k) a[k] += bf2f(hv[k]);
            }
        }
    }
#pragma unroll
    for (int off = 8; off < 64; off <<= 1) {
#pragma unroll
        for (int k = 0; k < 8; ++k) a[k] += __shfl_xor(a[k], off, 64);
    }
    if (g == 0 && l < 5) {
        float d = dinv[node];
        float d2 = d * d;
        us8 o;
        if (ADDIN) {
            us8 ad = *(const us8*)&addin[(size_t)node * 40 + l * 8];
#pragma unroll
            for (int k = 0; k < 8; ++k) o[k] = f2bf(bf2f(ad[k]) + d2 * a[k]);
        } else {
#pragma unroll
            for (int k = 0; k < 8; ++k) o[k] = f2bf(d2 * a[k]);
        }
        *(us8*)&out[(size_t)node * 40 + l * 8] = o;
    }
}

// ---------------- final prop40 + log_softmax fused ----------------
// EPILOGUE RUNS ON GROUP 0 ONLY: after the full butterfly the sums are
// replicated across all 8 groups — round-16 ran the u0 loads + 8 expf/lane on
// all groups (8x redundant VALU, 85% VALUBusy, 60us). Group 0's lanes 0-7 are
// all active inside the branch, so the intra-group shfl_xor(1,2,4) reductions
// only reference active lanes.

__global__ __launch_bounds__(256) void prop40lsm_kernel(const int* __restrict__ rowptr,
                                                        const int* __restrict__ srcarr,
                                                        const float* __restrict__ dinv,
                                                        const unsigned short* __restrict__ in,
                                                        const float* __restrict__ bias,
                                                        float* __restrict__ out, int N) {
    int gid = blockIdx.x * blockDim.x + threadIdx.x;
    int node = gid >> 6;
    if (node >= N) return;
    int lane = threadIdx.x & 63;
    int g = lane >> 3, l = lane & 7;
    int beg = rowptr[node], end = rowptr[node + 1];
    int deg = end - beg;
    float a[8] = {};
    for (int chunk = 0; chunk < deg; chunk += 64) {
        int lim = min(64, deg - chunk);
        int src_l = (lane < lim) ? srcarr[beg + chunk + lane] : 0;
        int iters = (lim + 7) >> 3;
        for (int t = 0; t < iters; ++t) {
            int jj = g + (t << 3);
            int src = __shfl(src_l, jj, 64);
            if (jj < lim && l < 5) {
                us8 hv = *(const us8*)&in[(size_t)src * 40 + l * 8];
#pragma unroll
                for (int k = 0; k < 8; ++k) a[k] += bf2f(hv[k]);
            }
        }
    }
#pragma unroll
    for (int off = 8; off < 64; off <<= 1) {
#pragma unroll
        for (int k = 0; k < 8; ++k) a[k] += __shfl_xor(a[k], off, 64);
    }
    if (g == 0) {  // sums replicated across groups: epilogue on group 0 only
        float d = dinv[node];
        float v[8];
        float m = -INFINITY;
        if (l < 5) {
            float4 u0a = *(const float4*)&out[(size_t)node * 40 + l * 8];
            float4 u0b = *(const float4*)&out[(size_t)node * 40 + l * 8 + 4];
            float ub[8] = {u0a.x, u0a.y, u0a.z, u0a.w, u0b.x, u0b.y, u0b.z, u0b.w};
#pragma unroll
            for (int k = 0; k < 8; ++k) {
                v[k] = ub[k] + d * a[k] + bias[l * 8 + k];
                m = fmaxf(m, v[k]);
            }
        }
        m = fmaxf(m, __shfl_xor(m, 1, 64));
        m = fmaxf(m, __shfl_xor(m, 2, 64));
        m = fmaxf(m, __shfl_xor(m, 4, 64));
        float e = 0.0f;
        if (l < 5) {
#pragma unroll
            for (int k = 0; k < 8; ++k) e += expf(v[k] - m);
        }
        e += __shfl_xor(e, 1, 64);
        e += __shfl_xor(e, 2, 64);
        e += __shfl_xor(e, 4, 64);
        if (l < 5) {
            float ls = m + logf(e);
            float4 oa = make_float4(v[0] - ls, v[1] - ls, v[2] - ls, v[3] - ls);
            float4 ob = make_float4(v[4] - ls, v[5] - ls, v[6] - ls, v[7] - ls);
            *(float4*)&out[(size_t)node * 40 + l * 8] = oa;
            *(float4*)&out[(size_t)node * 40 + l * 8 + 4] = ob;
        }
    }
}

// ---------------- W prep: f32 [4][64][DOUTsrc] -> bf16 MFMA B-fragments ----------------

__global__ void wprep_kernel(const float* __restrict__ W, unsigned short* __restrict__ Wb,
                             int DOUTsrc, int CT) {
    int idx = blockIdx.x * blockDim.x + threadIdx.x;
    int total = 4 * 2 * CT * 64;
    if (idx >= total) return;
    int lane = idx & 63;
    int rest = idx >> 6;              // (kk*2+ks)*CT + ct
    int ct = rest % CT;
    int tmp = rest / CT;
    int ks = tmp & 1, kk = tmp >> 1;
    int colc = ct * 16 + (lane & 15);
    int k0 = ks * 32 + (lane >> 4) * 8;
    us8 ov;
#pragma unroll
    for (int j = 0; j < 8; ++j) {
        float v = (colc < DOUTsrc) ? W[(size_t)(kk * 64 + k0 + j) * DOUTsrc + colc] : 0.0f;
        ov[j] = f2bf(v);
    }
    *(us8*)&Wb[(size_t)idx * 8] = ov;
}

// ---------------- MFMA mm4 (layer 1): out = h0@W[0] + rdinv_row * sum_i s_i@W[i] ------

template <int CT, int MODE>
__global__ __launch_bounds__(256) void mm4m_kernel(const unsigned short* __restrict__ h0,
                                                   const unsigned short* __restrict__ s1,
                                                   const unsigned short* __restrict__ s2,
                                                   const unsigned short* __restrict__ s3,
                                                   const float* __restrict__ rdinv,
                                                   const float* __restrict__ dinv,
                                                   const unsigned short* __restrict__ Wb,
                                                   const float* __restrict__ bias,
                                                   float* __restrict__ outf,
                                                   unsigned short* __restrict__ outh,
                                                   unsigned short* __restrict__ outs, int N) {
    constexpr int LSTR = (MODE == 2) ? 68 : 52;
    __shared__ __align__(16) float Lds[64 * LSTR];
    int tid = threadIdx.x;
    int w = tid >> 6, lane = tid & 63;
    int row0 = blockIdx.x * 64 + w * 16;
    int arow = row0 + (lane & 15);
    bool aok = arow < N;
    size_t abase = (size_t)arow * DIN + ((lane >> 4) * 8);
    const unsigned short* hp[4] = {h0, s1, s2, s3};

    f32x4 acc0[CT] = {};
    f32x4 accS[CT] = {};
#pragma unroll
    for (int kk = 0; kk < 4; ++kk) {
        const unsigned short* hb = hp[kk];
#pragma unroll
        for (int ks = 0; ks < 2; ++ks) {
            s16x8 a = {};
            if (aok) a = *(const s16x8*)&hb[abase + ks * 32];
#pragma unroll
            for (int c = 0; c < CT; ++c) {
                s16x8 b = *(const s16x8*)&Wb[(size_t)(((kk * 2 + ks) * CT + c) * 64 + lane) * 8];
                if (kk == 0)
                    acc0[c] = __builtin_amdgcn_mfma_f32_16x16x32_bf16(a, b, acc0[c], 0, 0, 0);
                else
                    accS[c] = __builtin_amdgcn_mfma_f32_16x16x32_bf16(a, b, accS[c], 0, 0, 0);
            }
        }
    }
    int lcol = lane & 15;
    int lrow4 = (lane >> 4) * 4;
#pragma unroll
    for (int r = 0; r < 4; ++r) {
        int lr = lrow4 + r;
        int grow = row0 + lr;
        float rd = (grow < N) ? rdinv[grow] : 0.0f;
#pragma unroll
        for (int c = 0; c < CT; ++c) {
            float v = acc0[c][r] + rd * accS[c][r];
            if (MODE == 2) {
                v += bias[c * 16 + lcol];
                v = v > 0.0f ? v : 0.0f;
            }
            Lds[(w * 16 + lr) * LSTR + c * 16 + lcol] = v;
        }
    }
    __syncthreads();
    int rowsInBlk = min(64, N - blockIdx.x * 64);
    if (MODE == 2) {
        for (int idx = tid; idx < rowsInBlk * 8; idx += 256) {
            int r = idx >> 3, k8 = (idx & 7) * 8;
            int gr = blockIdx.x * 64 + r;
            us8 oh;
#pragma unroll
            for (int k = 0; k < 8; ++k) oh[k] = f2bf(Lds[r * LSTR + k8 + k]);
            *(us8*)&outh[(size_t)gr * DIN + k8] = oh;
            if (outs != nullptr) {
                float d = dinv[gr];
                us8 os;
#pragma unroll
                for (int k = 0; k < 8; ++k) os[k] = f2bf(d * Lds[r * LSTR + k8 + k]);
                *(us8*)&outs[(size_t)gr * DIN + k8] = os;
            }
        }
    } else {
        for (int idx = tid; idx < rowsInBlk * 10; idx += 256) {
            int r = idx / 10, c4 = idx - r * 10;
            int gr = blockIdx.x * 64 + r;
            float4 v = *(float4*)&Lds[r * LSTR + c4 * 4];
            *(float4*)&outf[(size_t)gr * 40 + c4 * 4] = v;
        }
    }
}

// ---------------- MFMA mmU (layer 2, Horner): U_k = P @ W2[k], k=0..3 ----------------

__global__ __launch_bounds__(256) void mmU_kernel(const unsigned short* __restrict__ P,
                                                  const float* __restrict__ dinv,
                                                  const unsigned short* __restrict__ Wb,
                                                  float* __restrict__ u0f,
                                                  unsigned short* __restrict__ u1,
                                                  unsigned short* __restrict__ u2,
                                                  unsigned short* __restrict__ u3, int N) {
    constexpr int CT = 3, LSTR = 52;
    __shared__ __align__(16) float Lds[64 * LSTR];
    int tid = threadIdx.x;
    int w = tid >> 6, lane = tid & 63;
    int row0 = blockIdx.x * 64 + w * 16;
    int arow = row0 + (lane & 15);
    bool aok = arow < N;
    size_t abase = (size_t)arow * DIN + ((lane >> 4) * 8);
    s16x8 a0 = {}, a1 = {};
    if (aok) {
        a0 = *(const s16x8*)&P[abase];
        a1 = *(const s16x8*)&P[abase + 32];
    }
    f32x4 acc[4][CT] = {};
#pragma unroll
    for (int kk = 0; kk < 4; ++kk) {
#pragma unroll
        for (int c = 0; c < CT; ++c) {
            s16x8 b0 = *(const s16x8*)&Wb[(size_t)(((kk * 2 + 0) * CT + c) * 64 + lane) * 8];
            s16x8 b1 = *(const s16x8*)&Wb[(size_t)(((kk * 2 + 1) * CT + c) * 64 + lane) * 8];
            acc[kk][c] = __builtin_amdgcn_mfma_f32_16x16x32_bf16(a0, b0, acc[kk][c], 0, 0, 0);
            acc[kk][c] = __builtin_amdgcn_mfma_f32_16x16x32_bf16(a1, b1, acc[kk][c], 0, 0, 0);
        }
    }
    int lcol = lane & 15;
    int lrow4 = (lane >> 4) * 4;
    int rowsInBlk = min(64, N - blockIdx.x * 64);
    unsigned short* up[4] = {nullptr, u1, u2, u3};
#pragma unroll
    for (int kk = 0; kk < 4; ++kk) {
#pragma unroll
        for (int r = 0; r < 4; ++r)
#pragma unroll
            for (int c = 0; c < CT; ++c)
                Lds[(w * 16 + lrow4 + r) * LSTR + c * 16 + lcol] = acc[kk][c][r];
        __syncthreads();
        if (kk == 0) {
            for (int idx = tid; idx < rowsInBlk * 10; idx += 256) {
                int r = idx / 10, c4 = idx - r * 10;
                int gr = blockIdx.x * 64 + r;
                float4 v = *(float4*)&Lds[r * LSTR + c4 * 4];
                *(float4*)&u0f[(size_t)gr * 40 + c4 * 4] = v;
            }
        } else {
            unsigned short* u = up[kk];
            for (int idx = tid; idx < rowsInBlk * 5; idx += 256) {
                int r = idx / 5, seg = idx - r * 5;
                int gr = blockIdx.x * 64 + r;
                float d = dinv[gr];
                us8 o;
#pragma unroll
                for (int k = 0; k < 8; ++k) o[k] = f2bf(d * Lds[r * LSTR + seg * 8 + k]);
                *(us8*)&u[(size_t)gr * 40 + seg * 8] = o;
            }
        }
        __syncthreads();
    }
}

// ---------------- launch ----------------

extern "C" void kernel_launch(void* const* d_in, const int* in_sizes, int n_in,
                              void* d_out, int out_size, void* d_ws, size_t ws_size,
                              hipStream_t stream) {
    const float* x  = (const float*)d_in[0];
    const int*   ei = (const int*)d_in[1];
    const float* W1 = (const float*)d_in[2];
    const float* b1 = (const float*)d_in[3];
    const float* W2 = (const float*)d_in[4];
    const float* b2 = (const float*)d_in[5];

    int N = in_sizes[0] / DIN;
    int E = in_sizes[1] / 2;
    const int* rowv = ei;       // edge_index[0] = message source
    const int* colv = ei + E;   // edge_index[1] = destination (segment id)
    int NB = (N + 255) >> 8;

    char* p = (char*)d_ws;
    auto alloc = [&](size_t bytes) {
        char* q = p;
        p += (bytes + 255) & ~(size_t)255;
        return q;
    };
    int*   bcnt   = (int*)alloc(NB_MAX * 4);
    int*   bbase  = (int*)alloc((NB_MAX + 1) * 4);
    int*   gcur   = (int*)alloc(NB_MAX * 4);
    int*   rowptr = (int*)alloc((size_t)(N + 1) * 4);
    float* dinv   = (float*)alloc((size_t)N * 4);
    float* rdinv  = (float*)alloc((size_t)N * 4);
    int*   sorted = (int*)alloc((size_t)E * 4);
    int*   srcarr = (int*)alloc((size_t)E * 4);
    unsigned short* Wb1 = (unsigned short*)alloc((size_t)4 * 2 * 4 * 64 * 8 * 2);
    unsigned short* Wb2 = (unsigned short*)alloc((size_t)4 * 2 * 3 * 64 * 8 * 2);
    unsigned short* hb0 = (unsigned short*)alloc((size_t)N * DIN * 2);
    unsigned short* hbE = (unsigned short*)alloc((size_t)N * DIN * 2);
    unsigned short* sbA = (unsigned short*)alloc((size_t)N * DIN * 2);
    unsigned short* sbB = (unsigned short*)alloc((size_t)N * DIN * 2);
    unsigned short* sbC = (unsigned short*)alloc((size_t)N * DIN * 2);
    unsigned short* sbD = (unsigned short*)alloc((size_t)N * DIN * 2);
    unsigned short* u1  = (unsigned short*)alloc((size_t)N * 40 * 2);
    unsigned short* u2  = (unsigned short*)alloc((size_t)N * 40 * 2);
    unsigned short* u3  = (unsigned short*)alloc((size_t)N * 40 * 2);
    unsigned short* t40A = (unsigned short*)alloc((size_t)N * 40 * 2);
    unsigned short* t40B = (unsigned short*)alloc((size_t)N * 40 * 2);
    float* outp   = (float*)d_out;

    hipMemsetAsync(bcnt, 0, NB_MAX * 4, stream);

    const int tpb = 256;

    bcount_kernel<<<128, tpb, 0, stream>>>(colv, bcnt, E, NB);
    bscan_kernel<<<1, 512, 0, stream>>>(bcnt, bbase, gcur, rowptr, NB, N, E);
    s1_bucket<<<(E + S1_CHUNK - 1) / S1_CHUNK, 256, 0, stream>>>(rowv, colv, gcur, sorted, E, NB);
    s2_kernel<<<NB, 256, 0, stream>>>(sorted, bbase, rowptr, dinv, rdinv, srcarr, N);
    wprep_kernel<<<8, tpb, 0, stream>>>(W1, Wb1, 64, 4);
    wprep_kernel<<<6, tpb, 0, stream>>>(W2, Wb2, 40, 3);

    int propBlocks = (N * 64 + tpb - 1) / tpb;  // one wave per node
    int mmBlocks = (N + 63) / 64;
    int n4 = N * 16;
    cvt_kernel<<<(n4 + tpb - 1) / tpb, tpb, 0, stream>>>(x, dinv, hb0, sbA, n4);  // sbA = sb0

    // ---- layer 1: h = relu(x@W1[0] + A x@W1[1] + A^2 x@W1[2] + A^3 x@W1[3] + b1) -> hbE
    prop_kernel<<<propBlocks, tpb, 0, stream>>>(rowptr, srcarr, dinv, sbA, sbB, N);  // sb1
    prop_kernel<<<propBlocks, tpb, 0, stream>>>(rowptr, srcarr, dinv, sbB, sbC, N);  // sb2
    prop_kernel<<<propBlocks, tpb, 0, stream>>>(rowptr, srcarr, dinv, sbC, sbD, N);  // sb3
    mm4m_kernel<4, 2><<<mmBlocks, 256, 0, stream>>>(hb0, sbB, sbC, sbD, rdinv, dinv,
                                                    Wb1, b1, nullptr, hbE, nullptr, N);

    // ---- layer 2 (Horner on 40-dim): out = log_softmax(U0 + A(U1 + A(U2 + A*U3)) + b2)
    mmU_kernel<<<mmBlocks, 256, 0, stream>>>(hbE, dinv, Wb2, outp, u1, u2, u3, N);
    prop40_kernel<true><<<propBlocks, tpb, 0, stream>>>(rowptr, srcarr, dinv, u3, u2, t40A, N);
    prop40_kernel<true><<<propBlocks, tpb, 0, stream>>>(rowptr, srcarr, dinv, t40A, u1, t40B, N);
    prop40lsm_kernel<<<propBlocks, tpb, 0, stream>>>(rowptr, srcarr, dinv, t40B, b2, outp, N);
}

// Round 19
// 383.098 us; speedup vs baseline: 1.0140x; 1.0140x over previous
//
#include <hip/hip_runtime.h>
#include <math.h>

#define DIN 64
#define NB_MAX 512   // buckets of 256 nodes: supports N <= 131072
#define S1_CHUNK 4096

typedef unsigned short us8 __attribute__((ext_vector_type(8)));
typedef short s16x8 __attribute__((ext_vector_type(8)));
typedef float f32x4 __attribute__((ext_vector_type(4)));

// ---------------- bf16 helpers (RNE) ----------------

__device__ __forceinline__ float bf2f(unsigned short u) {
    return __uint_as_float(((unsigned int)u) << 16);
}
__device__ __forceinline__ unsigned short f2bf(float f) {
    unsigned int u = __float_as_uint(f);
    return (unsigned short)((u + 0x7fffu + ((u >> 16) & 1u)) >> 16);
}

// ---------------- per-BUCKET histogram ----------------

__global__ __launch_bounds__(256) void bcount_kernel(const int* __restrict__ col,
                                                     int* __restrict__ bcnt, int E, int NB) {
    __shared__ int cntB[NB_MAX];
    for (int t = threadIdx.x; t < NB; t += 256) cntB[t] = 0;
    __syncthreads();
    int stride = gridDim.x * blockDim.x;
    for (int i = blockIdx.x * blockDim.x + threadIdx.x; i < E; i += stride)
        atomicAdd(&cntB[col[i] >> 8], 1);
    __syncthreads();
    for (int t = threadIdx.x; t < NB; t += 256) {
        int c = cntB[t];
        if (c) atomicAdd(&bcnt[t], c);
    }
}

__global__ void bscan_kernel(const int* __restrict__ bcnt, int* __restrict__ bbase,
                             int* __restrict__ gcur, int* __restrict__ rowptr,
                             int NB, int N, int E) {
    __shared__ int sm[512];
    int tid = threadIdx.x;
    int v = (tid < NB) ? bcnt[tid] : 0;
    sm[tid] = v;
    __syncthreads();
    for (int off = 1; off < 512; off <<= 1) {
        int add = (tid >= off) ? sm[tid - off] : 0;
        __syncthreads();
        sm[tid] += add;
        __syncthreads();
    }
    if (tid < NB) { int b = sm[tid] - v; bbase[tid] = b; gcur[tid] = b; }
    if (tid == NB - 1) bbase[NB] = sm[tid];
    if (tid == 0) rowptr[N] = E;
}

// ---------------- S1: bucket scatter (entry packed (src<<8)|(dest&255)) ----------------

__global__ __launch_bounds__(256) void s1_bucket(const int* __restrict__ row,
                                                 const int* __restrict__ col,
                                                 int* __restrict__ gcur,
                                                 int* __restrict__ sorted, int E, int NB) {
    __shared__ int2 ebuf[S1_CHUNK];      // 32KB
    __shared__ int cntL[NB_MAX];
    __shared__ int baseL[NB_MAX];
    __shared__ int curL[NB_MAX];
    __shared__ int gbaseL[NB_MAX];
    __shared__ int sm[256];
    int tid = threadIdx.x;
    int jb = blockIdx.x * S1_CHUNK;
    int je = min(jb + S1_CHUNK, E);
    int cntTot = je - jb;

    for (int t = tid; t < NB; t += 256) cntL[t] = 0;
    __syncthreads();
    for (int j = jb + tid; j < je; j += 256) atomicAdd(&cntL[col[j] >> 8], 1);
    __syncthreads();
    int per = (NB + 255) >> 8;
    int s = 0;
    for (int q = 0; q < per; ++q) {
        int idx = tid * per + q;
        if (idx < NB) s += cntL[idx];
    }
    sm[tid] = s;
    __syncthreads();
    for (int off = 1; off < 256; off <<= 1) {
        int add = (tid >= off) ? sm[tid - off] : 0;
        __syncthreads();
        sm[tid] += add;
        __syncthreads();
    }
    int run = sm[tid] - s;
    for (int q = 0; q < per; ++q) {
        int idx = tid * per + q;
        if (idx < NB) { baseL[idx] = run; curL[idx] = run; run += cntL[idx]; }
    }
    __syncthreads();
    for (int t = tid; t < NB; t += 256)
        gbaseL[t] = atomicAdd(&gcur[t], cntL[t]);
    for (int j = jb + tid; j < je; j += 256) {
        int c = col[j];
        int pos = atomicAdd(&curL[c >> 8], 1);
        ebuf[pos] = make_int2(row[j], c);
    }
    __syncthreads();
    for (int jj = tid; jj < cntTot; jj += 256) {
        int2 e = ebuf[jj];
        int t = e.y >> 8;
        sorted[gbaseL[t] + (jj - baseL[t])] = (e.x << 8) | (e.y & 255);
    }
}

// ---------------- S2: per-bucket counts + rowptr + dinv/rdinv + src placement --------

__global__ __launch_bounds__(256) void s2_kernel(const int* __restrict__ sorted,
                                                 const int* __restrict__ bbase,
                                                 int* __restrict__ rowptr,
                                                 float* __restrict__ dinv,
                                                 float* __restrict__ rdinv,
                                                 int* __restrict__ srcarr, int N) {
    __shared__ int cntL[256], baseL[256], sm[256];
    int tid = threadIdx.x;
    int b = blockIdx.x;
    int c0 = b << 8;
    int nLoc = min(256, N - c0);
    int gs = bbase[b], ge = bbase[b + 1];
    cntL[tid] = 0;
    __syncthreads();
    for (int j = gs + tid; j < ge; j += 256)
        atomicAdd(&cntL[sorted[j] & 255], 1);
    __syncthreads();
    int c = cntL[tid];
    sm[tid] = c;
    __syncthreads();
    for (int off = 1; off < 256; off <<= 1) {
        int add = (tid >= off) ? sm[tid - off] : 0;
        __syncthreads();
        sm[tid] += add;
        __syncthreads();
    }
    int base = gs + sm[tid] - c;
    baseL[tid] = base;
    if (tid < nLoc) {
        rowptr[c0 + tid] = base;
        dinv[c0 + tid] = (c > 0) ? rsqrtf((float)c) : 0.0f;
        rdinv[c0 + tid] = (c > 0) ? sqrtf((float)c) : 0.0f;
    }
    cntL[tid] = 0;  // reuse as cursor
    __syncthreads();
    for (int j = gs + tid; j < ge; j += 256) {
        int e = sorted[j];
        int cl = e & 255;
        int p = baseL[cl] + atomicAdd(&cntL[cl], 1);
        srcarr[p] = e >> 8;
    }
}

// ---------------- cvt: x -> hb0 (bf16) and sb0 = dinv*x ----------------

__global__ void cvt_kernel(const float* __restrict__ x, const float* __restrict__ dinv,
                           unsigned short* __restrict__ hb0, unsigned short* __restrict__ sb0,
                           int n4) {
    int i = blockIdx.x * blockDim.x + threadIdx.x;
    if (i >= n4) return;
    float d = dinv[i >> 4];
    float4 v = *(const float4*)&x[(size_t)i * 4];
    ushort4 h, s;
    h.x = f2bf(v.x); h.y = f2bf(v.y); h.z = f2bf(v.z); h.w = f2bf(v.w);
    s.x = f2bf(d * v.x); s.y = f2bf(d * v.y); s.z = f2bf(d * v.z); s.w = f2bf(d * v.w);
    *(ushort4*)&hb0[(size_t)i * 4] = h;
    *(ushort4*)&sb0[(size_t)i * 4] = s;
}

// ---------------- propagation, 64-dim (layer 1) ----------------

__global__ __launch_bounds__(256) void prop_kernel(const int* __restrict__ rowptr,
                                                   const int* __restrict__ srcarr,
                                                   const float* __restrict__ dinv,
                                                   const unsigned short* __restrict__ sb_in,
                                                   unsigned short* __restrict__ sb_out, int N) {
    int gid = blockIdx.x * blockDim.x + threadIdx.x;
    int node = gid >> 6;
    if (node >= N) return;
    int lane = threadIdx.x & 63;
    int g = lane >> 3, l = lane & 7;
    int beg = rowptr[node], end = rowptr[node + 1];
    int deg = end - beg;
    float a[8] = {};
    for (int chunk = 0; chunk < deg; chunk += 64) {
        int lim = min(64, deg - chunk);           // wave-uniform
        int src_l = (lane < lim) ? srcarr[beg + chunk + lane] : 0;
        int iters = (lim + 7) >> 3;               // wave-uniform
        for (int t = 0; t < iters; ++t) {
            int jj = g + (t << 3);
            int src = __shfl(src_l, jj, 64);      // all 64 lanes active
            if (jj < lim) {
                us8 hv = *(const us8*)&sb_in[(size_t)src * DIN + l * 8];
#pragma unroll
                for (int k = 0; k < 8; ++k) a[k] += bf2f(hv[k]);
            }
        }
    }
#pragma unroll
    for (int off = 8; off < 64; off <<= 1) {
#pragma unroll
        for (int k = 0; k < 8; ++k) a[k] += __shfl_xor(a[k], off, 64);
    }
    if (g == 0) {
        float d = dinv[node];
        float d2 = d * d;
        us8 o;
#pragma unroll
        for (int k = 0; k < 8; ++k) o[k] = f2bf(d2 * a[k]);
        *(us8*)&sb_out[(size_t)node * DIN + l * 8] = o;
    }
}

// ---------------- propagation, 40-dim packed (layer 2, Horner) ----------------

template <bool ADDIN>
__global__ __launch_bounds__(256) void prop40_kernel(const int* __restrict__ rowptr,
                                                     const int* __restrict__ srcarr,
                                                     const float* __restrict__ dinv,
                                                     const unsigned short* __restrict__ in,
                                                     const unsigned short* __restrict__ addin,
                                                     unsigned short* __restrict__ out, int N) {
    int gid = blockIdx.x * blockDim.x + threadIdx.x;
    int node = gid >> 6;
    if (node >= N) return;
    int lane = threadIdx.x & 63;
    int g = lane >> 3, l = lane & 7;
    int beg = rowptr[node], end = rowptr[node + 1];
    int deg = end - beg;
    float a[8] = {};
    for (int chunk = 0; chunk < deg; chunk += 64) {
        int lim = min(64, deg - chunk);
        int src_l = (lane < lim) ? srcarr[beg + chunk + lane] : 0;
        int iters = (lim + 7) >> 3;
        for (int t = 0; t < iters; ++t) {
            int jj = g + (t << 3);
            int src = __shfl(src_l, jj, 64);      // all lanes active
            if (jj < lim && l < 5) {
                us8 hv = *(const us8*)&in[(size_t)src * 40 + l * 8];
#pragma unroll
                for (int k = 0; k < 8; ++k) a[k] += bf2f(hv[k]);
            }
        }
    }
#pragma unroll
    for (int off = 8; off < 64; off <<= 1) {
#pragma unroll
        for (int k = 0; k < 8; ++k) a[k] += __shfl_xor(a[k], off, 64);
    }
    if (g == 0 && l < 5) {
        float d = dinv[node];
        float d2 = d * d;
        us8 o;
        if (ADDIN) {
            us8 ad = *(const us8*)&addin[(size_t)node * 40 + l * 8];
#pragma unroll
            for (int k = 0; k < 8; ++k) o[k] = f2bf(bf2f(ad[k]) + d2 * a[k]);
        } else {
#pragma unroll
            for (int k = 0; k < 8; ++k) o[k] = f2bf(d2 * a[k]);
        }
        *(us8*)&out[(size_t)node * 40 + l * 8] = o;
    }
}

// ---------------- final prop40 + log_softmax fused ----------------
// The epilogue executes ONCE per wave regardless of exec mask (lane-guarding
// saves no issue slots — round-17 lesson). The instruction-count lever is the
// transcendental: libm expf is ~25 branchy VALU instrs; __expf/__logf map to
// single v_exp_f32/v_log_f32 (+scale) — epilogue ~230 -> ~40 instrs/wave.

__global__ __launch_bounds__(256) void prop40lsm_kernel(const int* __restrict__ rowptr,
                                                        const int* __restrict__ srcarr,
                                                        const float* __restrict__ dinv,
                                                        const unsigned short* __restrict__ in,
                                                        const float* __restrict__ bias,
                                                        float* __restrict__ out, int N) {
    int gid = blockIdx.x * blockDim.x + threadIdx.x;
    int node = gid >> 6;
    if (node >= N) return;
    int lane = threadIdx.x & 63;
    int g = lane >> 3, l = lane & 7;
    int beg = rowptr[node], end = rowptr[node + 1];
    int deg = end - beg;
    float a[8] = {};
    for (int chunk = 0; chunk < deg; chunk += 64) {
        int lim = min(64, deg - chunk);
        int src_l = (lane < lim) ? srcarr[beg + chunk + lane] : 0;
        int iters = (lim + 7) >> 3;
        for (int t = 0; t < iters; ++t) {
            int jj = g + (t << 3);
            int src = __shfl(src_l, jj, 64);
            if (jj < lim && l < 5) {
                us8 hv = *(const us8*)&in[(size_t)src * 40 + l * 8];
#pragma unroll
                for (int k = 0; k < 8; ++k) a[k] += bf2f(hv[k]);
            }
        }
    }
#pragma unroll
    for (int off = 8; off < 64; off <<= 1) {
#pragma unroll
        for (int k = 0; k < 8; ++k) a[k] += __shfl_xor(a[k], off, 64);
    }
    if (g == 0) {
        float d = dinv[node];
        float v[8];
        float m = -INFINITY;
        if (l < 5) {
            float4 u0a = *(const float4*)&out[(size_t)node * 40 + l * 8];
            float4 u0b = *(const float4*)&out[(size_t)node * 40 + l * 8 + 4];
            float ub[8] = {u0a.x, u0a.y, u0a.z, u0a.w, u0b.x, u0b.y, u0b.z, u0b.w};
#pragma unroll
            for (int k = 0; k < 8; ++k) {
                v[k] = ub[k] + d * a[k] + bias[l * 8 + k];
                m = fmaxf(m, v[k]);
            }
        }
        m = fmaxf(m, __shfl_xor(m, 1, 64));
        m = fmaxf(m, __shfl_xor(m, 2, 64));
        m = fmaxf(m, __shfl_xor(m, 4, 64));
        float e = 0.0f;
        if (l < 5) {
#pragma unroll
            for (int k = 0; k < 8; ++k) e += __expf(v[k] - m);
        }
        e += __shfl_xor(e, 1, 64);
        e += __shfl_xor(e, 2, 64);
        e += __shfl_xor(e, 4, 64);
        if (l < 5) {
            float ls = m + __logf(e);
            float4 oa = make_float4(v[0] - ls, v[1] - ls, v[2] - ls, v[3] - ls);
            float4 ob = make_float4(v[4] - ls, v[5] - ls, v[6] - ls, v[7] - ls);
            *(float4*)&out[(size_t)node * 40 + l * 8] = oa;
            *(float4*)&out[(size_t)node * 40 + l * 8 + 4] = ob;
        }
    }
}

// ---------------- W prep: f32 [4][64][DOUTsrc] -> bf16 MFMA B-fragments ----------------

__global__ void wprep_kernel(const float* __restrict__ W, unsigned short* __restrict__ Wb,
                             int DOUTsrc, int CT) {
    int idx = blockIdx.x * blockDim.x + threadIdx.x;
    int total = 4 * 2 * CT * 64;
    if (idx >= total) return;
    int lane = idx & 63;
    int rest = idx >> 6;              // (kk*2+ks)*CT + ct
    int ct = rest % CT;
    int tmp = rest / CT;
    int ks = tmp & 1, kk = tmp >> 1;
    int colc = ct * 16 + (lane & 15);
    int k0 = ks * 32 + (lane >> 4) * 8;
    us8 ov;
#pragma unroll
    for (int j = 0; j < 8; ++j) {
        float v = (colc < DOUTsrc) ? W[(size_t)(kk * 64 + k0 + j) * DOUTsrc + colc] : 0.0f;
        ov[j] = f2bf(v);
    }
    *(us8*)&Wb[(size_t)idx * 8] = ov;
}

// ---------------- MFMA mm4 (layer 1): out = h0@W[0] + rdinv_row * sum_i s_i@W[i] ------

template <int CT, int MODE>
__global__ __launch_bounds__(256) void mm4m_kernel(const unsigned short* __restrict__ h0,
                                                   const unsigned short* __restrict__ s1,
                                                   const unsigned short* __restrict__ s2,
                                                   const unsigned short* __restrict__ s3,
                                                   const float* __restrict__ rdinv,
                                                   const float* __restrict__ dinv,
                                                   const unsigned short* __restrict__ Wb,
                                                   const float* __restrict__ bias,
                                                   float* __restrict__ outf,
                                                   unsigned short* __restrict__ outh,
                                                   unsigned short* __restrict__ outs, int N) {
    constexpr int LSTR = (MODE == 2) ? 68 : 52;
    __shared__ __align__(16) float Lds[64 * LSTR];
    int tid = threadIdx.x;
    int w = tid >> 6, lane = tid & 63;
    int row0 = blockIdx.x * 64 + w * 16;
    int arow = row0 + (lane & 15);
    bool aok = arow < N;
    size_t abase = (size_t)arow * DIN + ((lane >> 4) * 8);
    const unsigned short* hp[4] = {h0, s1, s2, s3};

    f32x4 acc0[CT] = {};
    f32x4 accS[CT] = {};
#pragma unroll
    for (int kk = 0; kk < 4; ++kk) {
        const unsigned short* hb = hp[kk];
#pragma unroll
        for (int ks = 0; ks < 2; ++ks) {
            s16x8 a = {};
            if (aok) a = *(const s16x8*)&hb[abase + ks * 32];
#pragma unroll
            for (int c = 0; c < CT; ++c) {
                s16x8 b = *(const s16x8*)&Wb[(size_t)(((kk * 2 + ks) * CT + c) * 64 + lane) * 8];
                if (kk == 0)
                    acc0[c] = __builtin_amdgcn_mfma_f32_16x16x32_bf16(a, b, acc0[c], 0, 0, 0);
                else
                    accS[c] = __builtin_amdgcn_mfma_f32_16x16x32_bf16(a, b, accS[c], 0, 0, 0);
            }
        }
    }
    int lcol = lane & 15;
    int lrow4 = (lane >> 4) * 4;
#pragma unroll
    for (int r = 0; r < 4; ++r) {
        int lr = lrow4 + r;
        int grow = row0 + lr;
        float rd = (grow < N) ? rdinv[grow] : 0.0f;
#pragma unroll
        for (int c = 0; c < CT; ++c) {
            float v = acc0[c][r] + rd * accS[c][r];
            if (MODE == 2) {
                v += bias[c * 16 + lcol];
                v = v > 0.0f ? v : 0.0f;
            }
            Lds[(w * 16 + lr) * LSTR + c * 16 + lcol] = v;
        }
    }
    __syncthreads();
    int rowsInBlk = min(64, N - blockIdx.x * 64);
    if (MODE == 2) {
        for (int idx = tid; idx < rowsInBlk * 8; idx += 256) {
            int r = idx >> 3, k8 = (idx & 7) * 8;
            int gr = blockIdx.x * 64 + r;
            us8 oh;
#pragma unroll
            for (int k = 0; k < 8; ++k) oh[k] = f2bf(Lds[r * LSTR + k8 + k]);
            *(us8*)&outh[(size_t)gr * DIN + k8] = oh;
            if (outs != nullptr) {
                float d = dinv[gr];
                us8 os;
#pragma unroll
                for (int k = 0; k < 8; ++k) os[k] = f2bf(d * Lds[r * LSTR + k8 + k]);
                *(us8*)&outs[(size_t)gr * DIN + k8] = os;
            }
        }
    } else {
        for (int idx = tid; idx < rowsInBlk * 10; idx += 256) {
            int r = idx / 10, c4 = idx - r * 10;
            int gr = blockIdx.x * 64 + r;
            float4 v = *(float4*)&Lds[r * LSTR + c4 * 4];
            *(float4*)&outf[(size_t)gr * 40 + c4 * 4] = v;
        }
    }
}

// ---------------- MFMA mmU (layer 2, Horner): U_k = P @ W2[k], k=0..3 ----------------

__global__ __launch_bounds__(256) void mmU_kernel(const unsigned short* __restrict__ P,
                                                  const float* __restrict__ dinv,
                                                  const unsigned short* __restrict__ Wb,
                                                  float* __restrict__ u0f,
                                                  unsigned short* __restrict__ u1,
                                                  unsigned short* __restrict__ u2,
                                                  unsigned short* __restrict__ u3, int N) {
    constexpr int CT = 3, LSTR = 52;
    __shared__ __align__(16) float Lds[64 * LSTR];
    int tid = threadIdx.x;
    int w = tid >> 6, lane = tid & 63;
    int row0 = blockIdx.x * 64 + w * 16;
    int arow = row0 + (lane & 15);
    bool aok = arow < N;
    size_t abase = (size_t)arow * DIN + ((lane >> 4) * 8);
    s16x8 a0 = {}, a1 = {};
    if (aok) {
        a0 = *(const s16x8*)&P[abase];
        a1 = *(const s16x8*)&P[abase + 32];
    }
    f32x4 acc[4][CT] = {};
#pragma unroll
    for (int kk = 0; kk < 4; ++kk) {
#pragma unroll
        for (int c = 0; c < CT; ++c) {
            s16x8 b0 = *(const s16x8*)&Wb[(size_t)(((kk * 2 + 0) * CT + c) * 64 + lane) * 8];
            s16x8 b1 = *(const s16x8*)&Wb[(size_t)(((kk * 2 + 1) * CT + c) * 64 + lane) * 8];
            acc[kk][c] = __builtin_amdgcn_mfma_f32_16x16x32_bf16(a0, b0, acc[kk][c], 0, 0, 0);
            acc[kk][c] = __builtin_amdgcn_mfma_f32_16x16x32_bf16(a1, b1, acc[kk][c], 0, 0, 0);
        }
    }
    int lcol = lane & 15;
    int lrow4 = (lane >> 4) * 4;
    int rowsInBlk = min(64, N - blockIdx.x * 64);
    unsigned short* up[4] = {nullptr, u1, u2, u3};
#pragma unroll
    for (int kk = 0; kk < 4; ++kk) {
#pragma unroll
        for (int r = 0; r < 4; ++r)
#pragma unroll
            for (int c = 0; c < CT; ++c)
                Lds[(w * 16 + lrow4 + r) * LSTR + c * 16 + lcol] = acc[kk][c][r];
        __syncthreads();
        if (kk == 0) {
            for (int idx = tid; idx < rowsInBlk * 10; idx += 256) {
                int r = idx / 10, c4 = idx - r * 10;
                int gr = blockIdx.x * 64 + r;
                float4 v = *(float4*)&Lds[r * LSTR + c4 * 4];
                *(float4*)&u0f[(size_t)gr * 40 + c4 * 4] = v;
            }
        } else {
            unsigned short* u = up[kk];
            for (int idx = tid; idx < rowsInBlk * 5; idx += 256) {
                int r = idx / 5, seg = idx - r * 5;
                int gr = blockIdx.x * 64 + r;
                float d = dinv[gr];
                us8 o;
#pragma unroll
                for (int k = 0; k < 8; ++k) o[k] = f2bf(d * Lds[r * LSTR + seg * 8 + k]);
                *(us8*)&u[(size_t)gr * 40 + seg * 8] = o;
            }
        }
        __syncthreads();
    }
}

// ---------------- launch ----------------

extern "C" void kernel_launch(void* const* d_in, const int* in_sizes, int n_in,
                              void* d_out, int out_size, void* d_ws, size_t ws_size,
                              hipStream_t stream) {
    const float* x  = (const float*)d_in[0];
    const int*   ei = (const int*)d_in[1];
    const float* W1 = (const float*)d_in[2];
    const float* b1 = (const float*)d_in[3];
    const float* W2 = (const float*)d_in[4];
    const float* b2 = (const float*)d_in[5];

    int N = in_sizes[0] / DIN;
    int E = in_sizes[1] / 2;
    const int* rowv = ei;       // edge_index[0] = message source
    const int* colv = ei + E;   // edge_index[1] = destination (segment id)
    int NB = (N + 255) >> 8;

    char* p = (char*)d_ws;
    auto alloc = [&](size_t bytes) {
        char* q = p;
        p += (bytes + 255) & ~(size_t)255;
        return q;
    };
    int*   bcnt   = (int*)alloc(NB_MAX * 4);
    int*   bbase  = (int*)alloc((NB_MAX + 1) * 4);
    int*   gcur   = (int*)alloc(NB_MAX * 4);
    int*   rowptr = (int*)alloc((size_t)(N + 1) * 4);
    float* dinv   = (float*)alloc((size_t)N * 4);
    float* rdinv  = (float*)alloc((size_t)N * 4);
    int*   sorted = (int*)alloc((size_t)E * 4);
    int*   srcarr = (int*)alloc((size_t)E * 4);
    unsigned short* Wb1 = (unsigned short*)alloc((size_t)4 * 2 * 4 * 64 * 8 * 2);
    unsigned short* Wb2 = (unsigned short*)alloc((size_t)4 * 2 * 3 * 64 * 8 * 2);
    unsigned short* hb0 = (unsigned short*)alloc((size_t)N * DIN * 2);
    unsigned short* hbE = (unsigned short*)alloc((size_t)N * DIN * 2);
    unsigned short* sbA = (unsigned short*)alloc((size_t)N * DIN * 2);
    unsigned short* sbB = (unsigned short*)alloc((size_t)N * DIN * 2);
    unsigned short* sbC = (unsigned short*)alloc((size_t)N * DIN * 2);
    unsigned short* sbD = (unsigned short*)alloc((size_t)N * DIN * 2);
    unsigned short* u1  = (unsigned short*)alloc((size_t)N * 40 * 2);
    unsigned short* u2  = (unsigned short*)alloc((size_t)N * 40 * 2);
    unsigned short* u3  = (unsigned short*)alloc((size_t)N * 40 * 2);
    unsigned short* t40A = (unsigned short*)alloc((size_t)N * 40 * 2);
    unsigned short* t40B = (unsigned short*)alloc((size_t)N * 40 * 2);
    float* outp   = (float*)d_out;

    hipMemsetAsync(bcnt, 0, NB_MAX * 4, stream);

    const int tpb = 256;

    bcount_kernel<<<128, tpb, 0, stream>>>(colv, bcnt, E, NB);
    bscan_kernel<<<1, 512, 0, stream>>>(bcnt, bbase, gcur, rowptr, NB, N, E);
    s1_bucket<<<(E + S1_CHUNK - 1) / S1_CHUNK, 256, 0, stream>>>(rowv, colv, gcur, sorted, E, NB);
    s2_kernel<<<NB, 256, 0, stream>>>(sorted, bbase, rowptr, dinv, rdinv, srcarr, N);
    wprep_kernel<<<8, tpb, 0, stream>>>(W1, Wb1, 64, 4);
    wprep_kernel<<<6, tpb, 0, stream>>>(W2, Wb2, 40, 3);

    int propBlocks = (N * 64 + tpb - 1) / tpb;  // one wave per node
    int mmBlocks = (N + 63) / 64;
    int n4 = N * 16;
    cvt_kernel<<<(n4 + tpb - 1) / tpb, tpb, 0, stream>>>(x, dinv, hb0, sbA, n4);  // sbA = sb0

    // ---- layer 1: h = relu(x@W1[0] + A x@W1[1] + A^2 x@W1[2] + A^3 x@W1[3] + b1) -> hbE
    prop_kernel<<<propBlocks, tpb, 0, stream>>>(rowptr, srcarr, dinv, sbA, sbB, N);  // sb1
    prop_kernel<<<propBlocks, tpb, 0, stream>>>(rowptr, srcarr, dinv, sbB, sbC, N);  // sb2
    prop_kernel<<<propBlocks, tpb, 0, stream>>>(rowptr, srcarr, dinv, sbC, sbD, N);  // sb3
    mm4m_kernel<4, 2><<<mmBlocks, 256, 0, stream>>>(hb0, sbB, sbC, sbD, rdinv, dinv,
                                                    Wb1, b1, nullptr, hbE, nullptr, N);

    // ---- layer 2 (Horner on 40-dim): out = log_softmax(U0 + A(U1 + A(U2 + A*U3)) + b2)
    mmU_kernel<<<mmBlocks, 256, 0, stream>>>(hbE, dinv, Wb2, outp, u1, u2, u3, N);
    prop40_kernel<true><<<propBlocks, tpb, 0, stream>>>(rowptr, srcarr, dinv, u3, u2, t40A, N);
    prop40_kernel<true><<<propBlocks, tpb, 0, stream>>>(rowptr, srcarr, dinv, t40A, u1, t40B, N);
    prop40lsm_kernel<<<propBlocks, tpb, 0, stream>>>(rowptr, srcarr, dinv, t40B, b2, outp, N);
}